// Round 9
// baseline (55.724 us; speedup 1.0000x reference)
//
#include <hip/hip_runtime.h>
#include <stdint.h>

// IAF inversion via incremental MADE recurrence.
// 256 blocks x 4 waves (1 row/wave). Per-step 6KB packed weights staged ONCE
// per block into an 8-slot (48KB) LDS pipeline via global_load_lds:
//   during step u, wave (u&3) stages step u+8 into slot u&7 (just vacated),
//   and drains vmcnt(0) for its PREVIOUS stage (4 steps = ~1000+cyc old ->
//   never blocks, even at loaded-L2 latency ~900cyc).
// LDS->reg prefetch one step ahead via inline-asm ds_read_b128 (volatile
// outputs can't be sunk by the scheduler -- R7's C++ PREF was sunk, VGPR=48).
// One wait point per step: lgkmcnt(0)+sched_barrier BEFORE the s_barrier.
// DPP wave reduction; exp(-s)=2^(s') with -1/ln2 folded into weights.

#define Bz  1024
#define Dd  128
#define Hh  512
#define LN2 0.6931471805599453f
#define NRL -1.4426950408889634f   // -1/ln2

typedef float v4f __attribute__((ext_vector_type(4)));
typedef const __attribute__((address_space(1))) uint32_t* gas_t;
typedef __attribute__((address_space(3))) uint32_t* las_t;

// ---------------- DPP wave-64 sum ----------------
template<int CTRL, int RMASK>
__device__ __forceinline__ float dpp_add(float v) {
    int t = __builtin_amdgcn_update_dpp(0, __float_as_int(v), CTRL, RMASK, 0xf, true);
    return v + __int_as_float(t);
}
__device__ __forceinline__ float wave_sum_bcast(float v) {
    v = dpp_add<0x111, 0xf>(v);  // row_shr:1
    v = dpp_add<0x112, 0xf>(v);  // row_shr:2
    v = dpp_add<0x114, 0xf>(v);  // row_shr:4
    v = dpp_add<0x118, 0xf>(v);  // row_shr:8
    v = dpp_add<0x142, 0xa>(v);  // row_bcast:15
    v = dpp_add<0x143, 0xc>(v);  // row_bcast:31 -> lane63 = total
    return __int_as_float(__builtin_amdgcn_readlane(__float_as_int(v), 63));
}
__device__ __forceinline__ float bcast_lane(float v, int l) {
    return __int_as_float(__builtin_amdgcn_readlane(__float_as_int(v), l));
}

// ---------------- pre-pack masked weights (same layout as R7, verified) ----
__global__ void pack_kernel(const float* __restrict__ W1,
                            const float* __restrict__ W2,
                            float* __restrict__ Wp) {
    int idx = blockIdx.x * blockDim.x + threadIdx.x;
    if (idx >= Dd * 1536) return;
    int d = idx / 1536, f = idx % 1536;
    int seg = f >> 9, h = f & 511;
    int mh = (h % 127) + 1;
    float v;
    if (seg == 0)      v = W2[d * Hh + h]        * ((mh <= d) ? NRL : 0.f);
    else if (seg == 1) v = W2[(Dd + d) * Hh + h] * ((mh <= d) ? 1.f : 0.f);
    else               v = W1[h * Dd + d]        * ((mh >  d) ? 1.f : 0.f);
    int g = (f >> 2) & 127, e = f & 3;
    int G = g ^ ((g >> 3) & 7);
    Wp[d * 1536 + (seg << 9) + G * 4 + e] = v;
}

// ---------------- stage 6KB (one step) global -> LDS slot ----------------
__device__ __forceinline__ void stage6(const float* g, float* l) {
#pragma unroll
    for (int i = 0; i < 6; ++i)
        __builtin_amdgcn_global_load_lds((gas_t)(g + i * 256),
                                         (las_t)(l + i * 256), 16, 0, 0);
}

struct WB { v4f s0, s1, m0, m1, w0, w1; };

// ---------------- one recurrence step (weights in registers) -------------
__device__ __forceinline__ void computeStep(int u, int lane, const WB& w,
    float (&a)[8], float xa, float xb,
    float b2a, float b2b, float b2c, float b2d_,
    float &za, float &zb, float &ldet)
{
    float ps0 = 0.f, ps1 = 0.f, pm0 = 0.f, pm1 = 0.f;
#pragma unroll
    for (int k = 0; k < 4; ++k) {
        float hv = fmaxf(a[k], 0.f);
        ps0 = fmaf(hv, w.s0[k], ps0);
        pm0 = fmaf(hv, w.m0[k], pm0);
    }
#pragma unroll
    for (int k = 0; k < 4; ++k) {
        float hv = fmaxf(a[4 + k], 0.f);
        ps1 = fmaf(hv, w.s1[k], ps1);
        pm1 = fmaf(hv, w.m1[k], pm1);
    }
    float sp = wave_sum_bcast(ps0 + ps1);   // s' partial (= -s/ln2 part)
    float sm = wave_sum_bcast(pm0 + pm1);   // mu partial

    int dl = u & 63;
    float bs = bcast_lane(u < 64 ? b2a : b2b, dl);
    float bm = bcast_lane(u < 64 ? b2c : b2d_, dl);
    float xv = bcast_lane(u < 64 ? xa  : xb,  dl);

    float sd = sp + bs;                       // s' = -s/ln2
    float zd = (xv - (sm + bm)) * __builtin_amdgcn_exp2f(sd);
    ldet += sd;
    if (dl == lane) { if (u < 64) za = zd; else zb = zd; }

#pragma unroll
    for (int k = 0; k < 4; ++k) a[k]     = fmaf(zd, w.w0[k], a[k]);
#pragma unroll
    for (int k = 0; k < 4; ++k) a[4 + k] = fmaf(zd, w.w1[k], a[4 + k]);
}

__global__ __launch_bounds__(256, 1) void iaf8_kernel(
    const float* __restrict__ x,
    const float* __restrict__ b1,
    const float* __restrict__ b2,
    const float* __restrict__ Wp,
    float* __restrict__ out)
{
    __shared__ float lds[8 * 1536];            // 48 KB: 8 pipeline slots
    const int tid  = (int)threadIdx.x;
    const int lane = tid & 63;
    const int wid  = tid >> 6;                 // wave id 0..3
    const int row  = (int)blockIdx.x * 4 + wid;
    const int h0   = lane * 8;

    // ---- per-row state ----
    float a[8];
    {
        float4 t0 = *(const float4*)(b1 + h0);
        float4 t1 = *(const float4*)(b1 + h0 + 4);
        a[0]=t0.x; a[1]=t0.y; a[2]=t0.z; a[3]=t0.w;
        a[4]=t1.x; a[5]=t1.y; a[6]=t1.z; a[7]=t1.w;
    }
    float xa  = x[row * Dd + lane];
    float xb  = x[row * Dd + 64 + lane];
    float b2a = b2[lane] * NRL,  b2b = b2[64 + lane] * NRL;
    float b2c = b2[128 + lane],  b2d_ = b2[192 + lane];
    asm volatile("" : "+v"(xa), "+v"(xb), "+v"(b2a), "+v"(b2b), "+v"(b2c),
                      "+v"(b2d_), "+v"(a[0]), "+v"(a[1]), "+v"(a[2]),
                      "+v"(a[3]), "+v"(a[4]), "+v"(a[5]), "+v"(a[6]), "+v"(a[7]));

    // ---- swizzled reader LDS byte offsets (lane constants) ----
    const int g0 = 2 * lane, g1 = 2 * lane + 1;
    const int G0 = g0 ^ ((g0 >> 3) & 7);
    const int G1 = g1 ^ ((g1 >> 3) & 7);
    const unsigned lb0 = (unsigned)(uintptr_t)(las_t)(lds + G0 * 4);
    const unsigned lb1 = (unsigned)(uintptr_t)(las_t)(lds + G1 * 4);

    // ---- prologue: fill all 8 slots (wave w stages steps w and w+4) ----
    stage6(Wp + (size_t)wid * 1536 + lane * 4,       lds + wid * 1536);
    stage6(Wp + (size_t)(wid + 4) * 1536 + lane * 4, lds + (wid + 4) * 1536);
    asm volatile("s_waitcnt vmcnt(0)" ::: "memory");
    __builtin_amdgcn_sched_barrier(0);
    __builtin_amdgcn_s_barrier();
    __builtin_amdgcn_sched_barrier(0);

    float za = 0.f, zb = 0.f, ldet = 0.f;

    WB P, Q;

    // volatile asm ds_read_b128: outputs are pinned registers, cannot be sunk
#define PREF(SLOT, BUF) do {                                              \
        unsigned _a0 = lb0 + (unsigned)(SLOT) * 6144u;                    \
        unsigned _a1 = lb1 + (unsigned)(SLOT) * 6144u;                    \
        asm volatile("ds_read_b128 %0, %6 offset:0\n\t"                   \
                     "ds_read_b128 %1, %7 offset:0\n\t"                   \
                     "ds_read_b128 %2, %6 offset:2048\n\t"                \
                     "ds_read_b128 %3, %7 offset:2048\n\t"                \
                     "ds_read_b128 %4, %6 offset:4096\n\t"                \
                     "ds_read_b128 %5, %7 offset:4096"                    \
                     : "=v"(BUF.s0), "=v"(BUF.s1), "=v"(BUF.m0),          \
                       "=v"(BUF.m1), "=v"(BUF.w0), "=v"(BUF.w1)           \
                     : "v"(_a0), "v"(_a1));                               \
    } while (0)

    PREF(0, P);   // step 0 -> P (lgkm-waited at first loop top)

    // Step structure (per sub-step C, step u = t0+C):
    //  [stager: vmcnt(0) for its stage 4 steps ago -- never blocks]
    //  lgkmcnt(0) (my PREF from last step; issued ~1 step ago -- free)
    //  s_barrier   (publishes staged slots; orders reads vs restage)
    //  [stager: stage6(step u+8 -> slot u&7, just vacated)]
    //  PREF(step u+1 -> other buffer)   (asm, immovable)
    //  computeStep(u) from current buffer
#define SUB(C, CUR, NXT) do {                                             \
        const int u = t0 + (C);                                           \
        if (wid == ((C) & 3))                                             \
            asm volatile("s_waitcnt vmcnt(0)" ::: "memory");              \
        asm volatile("s_waitcnt lgkmcnt(0)" ::: "memory");                \
        __builtin_amdgcn_sched_barrier(0);                                \
        __builtin_amdgcn_s_barrier();                                     \
        __builtin_amdgcn_sched_barrier(0);                                \
        if (wid == ((C) & 3) && u + 8 < Dd)                               \
            stage6(Wp + (size_t)(u + 8) * 1536 + lane * 4,                \
                   lds + (C) * 1536);                                     \
        PREF((((C) + 1) & 7), NXT);                                       \
        computeStep(u, lane, CUR, a, xa, xb, b2a, b2b, b2c, b2d_,         \
                    za, zb, ldet);                                        \
    } while (0)

#pragma unroll 1
    for (int t0 = 0; t0 < Dd; t0 += 8) {
        SUB(0, P, Q);
        SUB(1, Q, P);
        SUB(2, P, Q);
        SUB(3, Q, P);
        SUB(4, P, Q);
        SUB(5, Q, P);
        SUB(6, P, Q);
        SUB(7, Q, P);
    }
#undef SUB
#undef PREF

    out[row * Dd + lane]      = za;
    out[row * Dd + 64 + lane] = zb;
    if (lane == 0) out[Bz * Dd + row] = LN2 * ldet;
}

// ---------------- fallback (ws too small): masked direct loads ----------------
__global__ __launch_bounds__(64, 1) void iaf_fb_kernel(
    const float* __restrict__ x,  const float* __restrict__ W1,
    const float* __restrict__ b1, const float* __restrict__ W2,
    const float* __restrict__ b2, float* __restrict__ out)
{
    const int lane = (int)threadIdx.x;
    const int row  = (int)blockIdx.x;
    const int h0   = lane * 8;
    float a[8]; int mh[8];
#pragma unroll
    for (int k = 0; k < 8; ++k) { a[k] = b1[h0 + k]; mh[k] = ((h0 + k) % 127) + 1; }
    float xa  = x[row * Dd + lane], xb = x[row * Dd + 64 + lane];
    float b2a = b2[lane], b2b = b2[64 + lane], b2c = b2[128 + lane], b2d_ = b2[192 + lane];
    float za = 0.f, zb = 0.f, ld = 0.f;
    for (int d = 0; d < Dd; ++d) {
        float ps = 0.f, pm = 0.f;
#pragma unroll
        for (int k = 0; k < 8; ++k) {
            float h = fmaxf(a[k], 0.f);
            h = (mh[k] <= d) ? h : 0.f;
            ps = fmaf(h, W2[d * Hh + h0 + k], ps);
            pm = fmaf(h, W2[(Dd + d) * Hh + h0 + k], pm);
        }
        ps = wave_sum_bcast(ps);
        pm = wave_sum_bcast(pm);
        int dl = d & 63;
        float sd = ps + bcast_lane(d < 64 ? b2a : b2b, dl);
        float md = pm + bcast_lane(d < 64 ? b2c : b2d_, dl);
        float xv =      bcast_lane(d < 64 ? xa  : xb,  dl);
        float zd = (xv - md) * __expf(-sd);
        ld -= sd;
        if (dl == lane) { if (d < 64) za = zd; else zb = zd; }
#pragma unroll
        for (int k = 0; k < 8; ++k)
            if (d < mh[k]) a[k] = fmaf(zd, W1[(h0 + k) * Dd + d], a[k]);
    }
    out[row * Dd + lane]      = za;
    out[row * Dd + 64 + lane] = zb;
    if (lane == 0) out[Bz * Dd + row] = ld;
}

extern "C" void kernel_launch(void* const* d_in, const int* in_sizes, int n_in,
                              void* d_out, int out_size, void* d_ws, size_t ws_size,
                              hipStream_t stream) {
    const float* x  = (const float*)d_in[0];
    const float* W1 = (const float*)d_in[1];
    const float* b1 = (const float*)d_in[2];
    const float* W2 = (const float*)d_in[3];
    const float* b2 = (const float*)d_in[4];
    float* out = (float*)d_out;
    float* Wp  = (float*)d_ws;

    const size_t need = (size_t)Dd * 1536 * sizeof(float);  // 768 KB
    if (ws_size >= need) {
        pack_kernel<<<(Dd * 1536 + 255) / 256, 256, 0, stream>>>(W1, W2, Wp);
        iaf8_kernel<<<Bz / 4, 256, 0, stream>>>(x, b1, b2, Wp, out);
    } else {
        iaf_fb_kernel<<<Bz, 64, 0, stream>>>(x, W1, b1, W2, b2, out);
    }
}